// Round 1
// baseline (305.876 us; speedup 1.0000x reference)
//
#include <hip/hip_runtime.h>

#define Bb 256
#define Tt 512
#define Ll 128
#define CH 16
#define NCH (Tt / CH)  // 32 chunks

// Barrier that waits only on LDS ops (lgkmcnt), NOT on in-flight global loads
// (__syncthreads would drain vmcnt(0) and kill the chunk prefetch cover).
__device__ __forceinline__ void bar_lgkm() {
  asm volatile("s_waitcnt lgkmcnt(0)" ::: "memory");
  __builtin_amdgcn_s_barrier();
  asm volatile("" ::: "memory");
}

__global__ __launch_bounds__(256) void crf_fused(
    const float* __restrict__ yt_g,   // y_true  (B,T,L) one-hot f32
    const float* __restrict__ yp_g,   // y_pred  (B,T,L) f32
    const float* __restrict__ tr_g,   // trans   (L,L)   f32
    float* __restrict__ out)          // (B,1)
{
  __shared__ __align__(16) float u_s[2][Ll];          // alpha in exp-domain, double-buffered
  __shared__ __align__(16) float emit_s[2][CH][Ll];   // y_pred chunk
  __shared__ __align__(16) float ytr_s[2][CH][Ll];    // y_true chunk
  __shared__ int   lab_s[Tt];
  __shared__ float redu[4], redp[4], redt[4];

  const int b   = blockIdx.x;
  const int tid = threadIdx.x;
  const int w   = tid >> 6;        // wave id 0..3
  const int l   = tid & 63;        // lane
  const int jj  = (w << 5) | (l & 31);  // output state 0..127 (each j held by 2 lanes)
  const int ih  = l >> 5;          // i-half: 0 -> i in [0,64), 1 -> i in [64,128)

  const float* yp_b = yp_g + (size_t)b * Tt * Ll;
  const float* yt_b = yt_g + (size_t)b * Tt * Ll;

  // ---- stage E = exp(trans) slice into registers: E[k] = exp(trans[64*ih+k][jj]) ----
  float E[64];
  #pragma unroll
  for (int k = 0; k < 64; ++k)
    E[k] = __expf(tr_g[(ih * 64 + k) * Ll + jj]);

  // ---- stage chunk 0 into LDS (blocking), issue chunk 1 prefetch ----
  float4 pend[4];
  {
    const float4* p1 = (const float4*)(yp_b);
    const float4* p2 = (const float4*)(yt_b);
    float4 a0 = p1[tid], a1 = p1[tid + 256];
    float4 b0 = p2[tid], b1 = p2[tid + 256];
    ((float4*)&emit_s[0][0][0])[tid]       = a0;
    ((float4*)&emit_s[0][0][0])[tid + 256] = a1;
    ((float4*)&ytr_s[0][0][0])[tid]        = b0;
    ((float4*)&ytr_s[0][0][0])[tid + 256]  = b1;
  }
  {
    const float4* p1 = (const float4*)(yp_b + CH * Ll);
    const float4* p2 = (const float4*)(yt_b + CH * Ll);
    pend[0] = p1[tid]; pend[1] = p1[tid + 256];
    pend[2] = p2[tid]; pend[3] = p2[tid + 256];
  }
  bar_lgkm();

  // ---- t = 0 init: u = exp(y_pred[:,0]); C = 0 ----
  float C_acc  = 0.f;
  float pt_acc = 0.f;
  float un     = 0.f;
  {
    float e0 = emit_s[0][0][jj];
    float y0 = ytr_s[0][0][jj];
    if (ih == 0) {
      u_s[0][jj] = __expf(e0);
      pt_acc = e0 * y0;
      if (y0 > 0.5f) lab_s[0] = jj;
    }
  }
  bar_lgkm();

  // ---- main recursion: 511 steps ----
  for (int t = 1; t < Tt; ++t) {
    const int c    = t >> 4;
    const int toff = t & (CH - 1);
    const int cb   = c & 1;

    if (toff == 0) {
      // write prefetched chunk c into its LDS buffer, then issue chunk c+1
      ((float4*)&emit_s[cb][0][0])[tid]       = pend[0];
      ((float4*)&emit_s[cb][0][0])[tid + 256] = pend[1];
      ((float4*)&ytr_s[cb][0][0])[tid]        = pend[2];
      ((float4*)&ytr_s[cb][0][0])[tid + 256]  = pend[3];
      bar_lgkm();
      if (c + 1 < NCH) {
        const float4* p1 = (const float4*)(yp_b + (size_t)(c + 1) * CH * Ll);
        const float4* p2 = (const float4*)(yt_b + (size_t)(c + 1) * CH * Ll);
        pend[0] = p1[tid]; pend[1] = p1[tid + 256];
        pend[2] = p2[tid]; pend[3] = p2[tid + 256];
      }
    }

    const int cur = (t - 1) & 1;
    float u0   = u_s[cur][0];                 // rescale pivot (LDS broadcast)
    float emit = emit_s[cb][toff][jj];
    float ytv  = ytr_s[cb][toff][jj];

    // mat-vec: s_j = sum_i u_i * E[i][jj]  (this thread does its 64-i half)
    float s0 = 0.f, s1 = 0.f, s2 = 0.f, s3 = 0.f;
    const float4* ub = (const float4*)&u_s[cur][ih << 6];
    #pragma unroll
    for (int kk = 0; kk < 16; ++kk) {
      float4 uu = ub[kk];
      s0 += uu.x * E[4 * kk + 0];
      s1 += uu.y * E[4 * kk + 1];
      s2 += uu.z * E[4 * kk + 2];
      s3 += uu.w * E[4 * kk + 3];
    }
    float s = (s0 + s1) + (s2 + s3);
    s += __shfl_xor(s, 32);                   // combine the two i-halves (same wave)

    float rinv = 1.0f / u0;
    un = s * rinv * __expf(emit);             // new u_j, rescaled by u0
    if (ih == 0) {
      u_s[t & 1][jj] = un;
      pt_acc += emit * ytv;                   // point score term
      if (ytv > 0.5f) lab_s[t] = jj;          // one-hot label detect
    }
    C_acc += __logf(u0);                      // running log-offset (uniform)
    bar_lgkm();
  }

  // ---- trans score from labels ----
  float tr_acc = 0.f;
  {
    int t2 = tid;
    if (t2 < Tt - 1) tr_acc += tr_g[lab_s[t2] * Ll + lab_s[t2 + 1]];
    t2 = tid + 256;
    if (t2 < Tt - 1) tr_acc += tr_g[lab_s[t2] * Ll + lab_s[t2 + 1]];
  }

  // ---- block reductions ----
  float usum = un, psum = pt_acc, tsum = tr_acc;
  #pragma unroll
  for (int off = 32; off; off >>= 1) {
    usum += __shfl_xor(usum, off);
    psum += __shfl_xor(psum, off);
    tsum += __shfl_xor(tsum, off);
  }
  if (l == 0) { redu[w] = usum; redp[w] = psum; redt[w] = tsum; }
  bar_lgkm();
  if (tid == 0) {
    float ut = (redu[0] + redu[1] + redu[2] + redu[3]) * 0.5f;  // each j counted twice
    float pt = redp[0] + redp[1] + redp[2] + redp[3];
    float tt = redt[0] + redt[1] + redt[2] + redt[3];
    out[b] = C_acc + __logf(ut) - pt - tt;
  }
}

extern "C" void kernel_launch(void* const* d_in, const int* in_sizes, int n_in,
                              void* d_out, int out_size, void* d_ws, size_t ws_size,
                              hipStream_t stream) {
  const float* y_true = (const float*)d_in[0];
  const float* y_pred = (const float*)d_in[1];
  const float* trans  = (const float*)d_in[2];
  float* out = (float*)d_out;
  crf_fused<<<dim3(Bb), dim3(256), 0, stream>>>(y_true, y_pred, trans, out);
}